// Round 7
// baseline (131.728 us; speedup 1.0000x reference)
//
#include <hip/hip_runtime.h>

// GAT forward, O(N*HD) via rank-decomposition (no sort!). B=8,N=1024,F=128,H=4,HD=32.
// score(i,j)=s_i+d_j; negative iff d_j < -s_i (exact: Sterbenz near cancellation).
// Per (b,h): rank each j by (d_j, j) lex (brute-force O(N^2) count, full-chip wide);
// scatter into sorted order. Then chunked prefix/suffix tables:
//   PB  = exclusive prefix of e^{0.2 d}*h  (negative branch)
//   SufA= inclusive suffix  of e^{d}*h     (positive branch)
//   out[i,:] = (c2*PB[k_i] + c1*SufA[k_i]) / (c2*PBs[k_i] + c1*SFs[k_i])
// k_i = lower_bound(dsrt, -s_i); c1=e^{s_i}, c2=e^{0.2 s_i}.

constexpr int CB  = 8;
constexpr int CN  = 1024;
constexpr int CF  = 128;
constexpr int CH  = 4;
constexpr int CHD = 32;
constexpr int CBH = CB * CH;        // 32
constexpr int CROWS = CB * CN;      // 8192
constexpr int TROWS = CN + 1;       // 1025 (row 1024 = zeros)

// ---------------- K1: projection + s/d ----------------
// 512 blocks x 256 thr; tile 16 rows x 128 cols; thread = (rp=tid>>5: 2 rows,
// c4=tid&31: 4 cols). x via padded LDS (broadcast reads, free); W via coalesced
// global float4 (L2-hot, 64 KB). VALU-bound: 1024 FMA/thread.
__global__ __launch_bounds__(256) void proj_kernel(
    const float* __restrict__ x, const float* __restrict__ W,
    const float* __restrict__ a_src, const float* __restrict__ a_dst,
    float* __restrict__ h_ws, float* __restrict__ sarr, float* __restrict__ darr)
{
    __shared__ __align__(16) float xs[16 * 132];   // 8.4 KB padded
    const int tid = threadIdx.x;
    const int row0 = blockIdx.x * 16;

    const float4* x4 = (const float4*)x;
    #pragma unroll
    for (int m = 0; m < 2; ++m) {
        const int idx = m * 256 + tid;              // 0..511
        const int r = idx >> 5, k4 = idx & 31;
        *(float4*)(xs + r * 132 + k4 * 4) = x4[(size_t)(row0 + r) * 32 + k4];
    }
    __syncthreads();

    const int c4 = tid & 31, rp = tid >> 5;         // cols c4*4.., rows rp*2..
    float acc0[4] = {0.f,0.f,0.f,0.f};
    float acc1[4] = {0.f,0.f,0.f,0.f};
    const float* xr0 = xs + (rp * 2) * 132;
    const float* xr1 = xs + (rp * 2 + 1) * 132;

    #pragma unroll 4
    for (int k4 = 0; k4 < 32; ++k4) {
        const float4 xv0 = *(const float4*)(xr0 + k4 * 4);   // broadcast, free
        const float4 xv1 = *(const float4*)(xr1 + k4 * 4);
        const float xq0[4] = {xv0.x, xv0.y, xv0.z, xv0.w};
        const float xq1[4] = {xv1.x, xv1.y, xv1.z, xv1.w};
        #pragma unroll
        for (int q = 0; q < 4; ++q) {
            const float4 wq = *(const float4*)(W + (size_t)(k4 * 4 + q) * CF + c4 * 4);
            acc0[0] += xq0[q] * wq.x; acc0[1] += xq0[q] * wq.y;
            acc0[2] += xq0[q] * wq.z; acc0[3] += xq0[q] * wq.w;
            acc1[0] += xq1[q] * wq.x; acc1[1] += xq1[q] * wq.y;
            acc1[2] += xq1[q] * wq.z; acc1[3] += xq1[q] * wq.w;
        }
    }

    // s/d partials from own 4 cols, butterfly over the 8 lanes of this head
    const float4 av = *(const float4*)(a_src + c4 * 4);
    const float4 dv = *(const float4*)(a_dst + c4 * 4);
    float s0 = acc0[0]*av.x + acc0[1]*av.y + acc0[2]*av.z + acc0[3]*av.w;
    float d0 = acc0[0]*dv.x + acc0[1]*dv.y + acc0[2]*dv.z + acc0[3]*dv.w;
    float s1 = acc1[0]*av.x + acc1[1]*av.y + acc1[2]*av.z + acc1[3]*av.w;
    float d1 = acc1[0]*dv.x + acc1[1]*dv.y + acc1[2]*dv.z + acc1[3]*dv.w;
    #pragma unroll
    for (int m = 1; m <= 4; m <<= 1) {              // lane-xor 1,2,4: stays in 8-group
        s0 += __shfl_xor(s0, m); d0 += __shfl_xor(d0, m);
        s1 += __shfl_xor(s1, m); d1 += __shfl_xor(d1, m);
    }

    const int head = c4 >> 3, dd0 = (c4 & 7) * 4;
    #pragma unroll
    for (int r2 = 0; r2 < 2; ++r2) {
        const int row = row0 + rp * 2 + r2, b = row >> 10, n = row & 1023;
        const int bh = b * CH + head;
        const float* a = r2 ? acc1 : acc0;
        *(float4*)(h_ws + (size_t)(bh * CN + n) * CHD + dd0)
            = make_float4(a[0], a[1], a[2], a[3]);
        if ((c4 & 7) == 0) {
            sarr[bh * CN + n] = r2 ? s1 : s0;
            darr[bh * CN + n] = r2 ? d1 : d0;
        }
    }
}

// ---------------- K2: brute-force rank + scatter (replaces bitonic sort) -------
// 256 blocks x 128 thr; block = (bh, oct of 128 i's). All-lanes-same LDS reads
// (broadcast). rank = #{j : (d_j,j) <lex (d_i,i)} -> unique in [0,1024).
__global__ __launch_bounds__(128) void rank_kernel(
    const float* __restrict__ darr, float* __restrict__ dsrt, int* __restrict__ perm,
    float* __restrict__ cfF, float* __restrict__ cfB)
{
    __shared__ __align__(16) float dsh[CN];
    const int bh = blockIdx.x >> 3, oct = blockIdx.x & 7;
    const int tid = threadIdx.x;
    for (int t = tid; t < CN; t += 128) dsh[t] = darr[bh * CN + t];
    __syncthreads();

    const int i = oct * 128 + tid;
    const float di = dsh[i];
    int cnt = 0;
    #pragma unroll 8
    for (int j4 = 0; j4 < 256; ++j4) {
        const float4 dj = *(const float4*)(dsh + j4 * 4);    // broadcast
        const int j0 = j4 * 4;
        cnt += (dj.x < di) || (dj.x == di && (j0 + 0) < i);
        cnt += (dj.y < di) || (dj.y == di && (j0 + 1) < i);
        cnt += (dj.z < di) || (dj.z == di && (j0 + 2) < i);
        cnt += (dj.w < di) || (dj.w == di && (j0 + 3) < i);
    }
    const int r = bh * CN + cnt;
    dsrt[r] = di;
    perm[r] = i;
    cfF[r] = __expf(0.2f * di);
    cfB[r] = __expf(di);
}

// ---------------- K3: chunk-local vector + scalar scans ----------------
// 256 blocks x 256 thr; block = (bh, g): 4 chunks of 32 sorted positions.
// thread = (sub, dir, dd). dir0: exclusive prefix of cfF*h; dir1: inclusive
// suffix of cfB*h. dd==0 lanes also carry the scalar scans.
__global__ __launch_bounds__(256) void scan_kernel(
    const float* __restrict__ h_ws, const int* __restrict__ perm,
    const float* __restrict__ cfF, const float* __restrict__ cfB,
    float* __restrict__ tbl_g, float* __restrict__ ct_g,
    float* __restrict__ spbL, float* __restrict__ ssfL, float* __restrict__ ctS_g)
{
    const int bh = blockIdx.x >> 3, g = blockIdx.x & 7;
    const int tid = threadIdx.x;
    const int sub = tid >> 6, dir = (tid >> 5) & 1, dd = tid & 31;
    const int c = g * 4 + sub;
    const int base = bh * CN + c * 32;
    const float* __restrict__ cf = dir ? cfB : cfF;
    const float* __restrict__ hb = h_ws + (size_t)bh * CN * CHD;
    float* __restrict__ tbl = tbl_g + (size_t)bh * TROWS * 64;

    float acc = 0.f, accS = 0.f;
    #pragma unroll
    for (int bt = 0; bt < 2; ++bt) {
        int jv[16]; float cv[16], hv[16];
        #pragma unroll
        for (int t = 0; t < 16; ++t) {
            const int p16 = bt * 16 + t;
            const int pos = dir ? (31 - p16) : p16;
            jv[t] = perm[base + pos];
            cv[t] = cf[base + pos];
        }
        #pragma unroll
        for (int t = 0; t < 16; ++t)
            hv[t] = hb[(size_t)jv[t] * CHD + dd];            // 16 gathers in flight
        #pragma unroll
        for (int t = 0; t < 16; ++t) {
            const int p16 = bt * 16 + t;
            const int pos = dir ? (31 - p16) : p16;
            const int prow = c * 32 + pos;
            if (dir == 0) {
                tbl[(size_t)prow * 64 + dd] = acc;           // exclusive prefix
                if (dd == 0) spbL[bh * CN + prow] = accS;
                acc  += cv[t] * hv[t];
                accS += cv[t];
            } else {
                acc  += cv[t] * hv[t];
                accS += cv[t];
                tbl[(size_t)prow * 64 + 32 + dd] = acc;      // inclusive suffix
                if (dd == 0) ssfL[bh * CN + prow] = accS;
            }
        }
    }
    ct_g[(size_t)((bh * 2 + dir) * 32 + c) * 32 + dd] = acc;
    if (dd == 0) ctS_g[(bh * 2 + dir) * 32 + c] = accS;
}

// ---------------- K4: chunk offsets + binary search + combine ----------------
// 256 blocks x 128 thr; block = (bh, oct of 128 i's). Offsets recomputed
// per block in LDS (cheap), tbl row 1024 zeroed redundantly (same value).
__global__ __launch_bounds__(128) void out_kernel(
    const float* __restrict__ sarr, const float* __restrict__ dsrt,
    const float* __restrict__ spbL, const float* __restrict__ ssfL,
    const float* __restrict__ ct_g, const float* __restrict__ ctS_g,
    float* __restrict__ tbl_g, float* __restrict__ out)
{
    __shared__ __align__(16) float dsS[CN];
    __shared__ float ctF[32 * 32], ctB[32 * 32];
    __shared__ float ofF[33 * 32], ofB[33 * 32];
    __shared__ float ctSF[32], ctSB[32], ofSF[33], ofSB[33];

    const int bh = blockIdx.x >> 3, oct = blockIdx.x & 7;
    const int tid = threadIdx.x;
    float* __restrict__ tbl = tbl_g + (size_t)bh * TROWS * 64;

    for (int t = tid; t < CN; t += 128) dsS[t] = dsrt[bh * CN + t];
    for (int t = tid; t < 1024; t += 128) {
        ctF[t] = ct_g[(size_t)(bh * 2 + 0) * 1024 + t];
        ctB[t] = ct_g[(size_t)(bh * 2 + 1) * 1024 + t];
    }
    if (tid < 32) {
        ctSF[tid] = ctS_g[(bh * 2 + 0) * 32 + tid];
        ctSB[tid] = ctS_g[(bh * 2 + 1) * 32 + tid];
    }
    if (tid < 64) tbl[(size_t)CN * 64 + tid] = 0.f;   // virtual row 1024
    __syncthreads();

    for (int idx = tid; idx < 33 * 32; idx += 128) {
        const int c = idx >> 5, dd = idx & 31;
        float rF = 0.f, rB = 0.f;
        for (int c2 = 0; c2 < c; ++c2)  rF += ctF[c2 * 32 + dd];
        for (int c2 = c + 1; c2 < 32; ++c2) rB += ctB[c2 * 32 + dd];
        ofF[idx] = rF;
        ofB[idx] = rB;
    }
    if (tid < 33) {
        float rF = 0.f, rB = 0.f;
        for (int c2 = 0; c2 < tid; ++c2) rF += ctSF[c2];
        for (int c2 = tid + 1; c2 < 32; ++c2) rB += ctSB[c2];
        ofSF[tid] = rF;
        ofSB[tid] = rB;
    }
    __syncthreads();

    const int i = oct * 128 + tid;
    const float s = sarr[bh * CN + i];
    const float c1 = __expf(s), c2v = __expf(0.2f * s), thr = -s;
    int lo = 0, hi = CN;
    while (lo < hi) { const int mid = (lo + hi) >> 1; if (dsS[mid] < thr) lo = mid + 1; else hi = mid; }
    const int k = lo, kc = k >> 5;                    // 0..32 (k==1024 -> 32)

    const float PBs = (k < CN ? spbL[bh * CN + k] : 0.f) + ofSF[kc];
    const float SFs = (k < CN ? ssfL[bh * CN + k] : 0.f) + ofSB[kc];
    const float inv = 1.0f / (c2v * PBs + c1 * SFs);

    const float4* tr = (const float4*)(tbl + (size_t)k * 64);
    const int b = bh >> 2, hh = bh & 3;
    float4* o = (float4*)(out + (size_t)(b * CN + i) * CF + hh * 32);
    #pragma unroll
    for (int q = 0; q < 8; ++q) {
        const float4 pb = tr[q], sf = tr[8 + q];
        const float4 oa = *(const float4*)(&ofF[kc * 32 + q * 4]);
        const float4 ob = *(const float4*)(&ofB[kc * 32 + q * 4]);
        float4 r;
        r.x = (c2v * (pb.x + oa.x) + c1 * (sf.x + ob.x)) * inv;
        r.y = (c2v * (pb.y + oa.y) + c1 * (sf.y + ob.y)) * inv;
        r.z = (c2v * (pb.z + oa.z) + c1 * (sf.z + ob.z)) * inv;
        r.w = (c2v * (pb.w + oa.w) + c1 * (sf.w + ob.w)) * inv;
        o[q] = r;
    }
}

extern "C" void kernel_launch(void* const* d_in, const int* in_sizes, int n_in,
                              void* d_out, int out_size, void* d_ws, size_t ws_size,
                              hipStream_t stream) {
    const float* x     = (const float*)d_in[0];
    const float* W     = (const float*)d_in[1];
    const float* a_src = (const float*)d_in[2];
    const float* a_dst = (const float*)d_in[3];
    float* out = (float*)d_out;

    char* ws = (char*)d_ws;
    size_t off = 0;
    float* h_ws = (float*)(ws + off); off += (size_t)CROWS * CF * 4;            // 4 MB
    float* sarr = (float*)(ws + off); off += (size_t)CBH * CN * 4;
    float* darr = (float*)(ws + off); off += (size_t)CBH * CN * 4;
    float* dsrt = (float*)(ws + off); off += (size_t)CBH * CN * 4;
    int*   perm = (int*)  (ws + off); off += (size_t)CBH * CN * 4;
    float* cfF  = (float*)(ws + off); off += (size_t)CBH * CN * 4;
    float* cfB  = (float*)(ws + off); off += (size_t)CBH * CN * 4;
    float* spbL = (float*)(ws + off); off += (size_t)CBH * CN * 4;
    float* ssfL = (float*)(ws + off); off += (size_t)CBH * CN * 4;
    float* ctg  = (float*)(ws + off); off += (size_t)CBH * 2 * 32 * 32 * 4;     // 256 KB
    float* ctSg = (float*)(ws + off); off += (size_t)CBH * 2 * 32 * 4;          // 8 KB
    float* tblg = (float*)(ws + off); off += (size_t)CBH * TROWS * 64 * 4;      // 8.4 MB
    (void)ws_size;

    proj_kernel<<<512, 256, 0, stream>>>(x, W, a_src, a_dst, h_ws, sarr, darr);
    rank_kernel<<<256, 128, 0, stream>>>(darr, dsrt, perm, cfF, cfB);
    scan_kernel<<<256, 256, 0, stream>>>(h_ws, perm, cfF, cfB, tblg, ctg, spbL, ssfL, ctSg);
    out_kernel<<<256, 128, 0, stream>>>(sarr, dsrt, spbL, ssfL, ctg, ctSg, tblg, out);
}